// Round 1
// baseline (4100.349 us; speedup 1.0000x reference)
//
#include <hip/hip_runtime.h>
#include <cstdint>

#define NV 50257
#define LS 50304   // padded logits row stride (786*64)
#define HD 512
#define G4 2048
#define BS 64
#define TE 256

__device__ __forceinline__ float sigm_f(float x) {
    x = fminf(fmaxf(x, -30.f), 30.f);
    return 1.f / (1.f + __expf(-x));
}
__device__ __forceinline__ float tanh_f(float x) {
    x = fminf(fmaxf(x, -15.f), 15.f);
    float e = __expf(2.f * x);
    return (e - 1.f) / (e + 1.f);
}

// X[t][b][j] = emb_row(t,b) . W_ih[j][:] + b_ih[j] + b_hh[j]
// grid: (nt, 32), block 256. One M-tile = one t (rows = b 0..63), N-tile = 64 j.
__global__ __launch_bounds__(256) void k_x(
    const int* __restrict__ lines, const int* __restrict__ tlines,
    const float* __restrict__ emb_in, const float* __restrict__ emb_tgt,
    const float* __restrict__ W_ih, const float* __restrict__ b_ih,
    const float* __restrict__ b_hh, float* __restrict__ Xbuf, int t0) {
    __shared__ float Ast[32][68];
    __shared__ float Bst[32][68];
    __shared__ const float* rowp[64];
    const int t = t0 + blockIdx.x;
    const int jt = blockIdx.y;
    const int tid = threadIdx.x;
    if (tid < 64) {
        int idx = (t < TE) ? lines[t * BS + tid] : tlines[tid];
        rowp[tid] = ((t < TE) ? emb_in : emb_tgt) + (long)idx * HD;
    }
    __syncthreads();
    const int tx = tid & 15, ty = tid >> 4;
    const int lr = tid >> 2;            // load row 0..63
    const int lc = (tid & 3) * 8;       // load col base in k-chunk
    const float* wrow = W_ih + (long)(jt * 64 + lr) * HD + lc;
    float acc[4][4] = {};
    for (int k0 = 0; k0 < HD; k0 += 32) {
        const float* ar = rowp[lr] + k0 + lc;
        float4 a0 = *(const float4*)ar;
        float4 a1 = *(const float4*)(ar + 4);
        float4 b0 = *(const float4*)(wrow + k0);
        float4 b1 = *(const float4*)(wrow + k0 + 4);
        Ast[lc + 0][lr] = a0.x; Ast[lc + 1][lr] = a0.y;
        Ast[lc + 2][lr] = a0.z; Ast[lc + 3][lr] = a0.w;
        Ast[lc + 4][lr] = a1.x; Ast[lc + 5][lr] = a1.y;
        Ast[lc + 6][lr] = a1.z; Ast[lc + 7][lr] = a1.w;
        Bst[lc + 0][lr] = b0.x; Bst[lc + 1][lr] = b0.y;
        Bst[lc + 2][lr] = b0.z; Bst[lc + 3][lr] = b0.w;
        Bst[lc + 4][lr] = b1.x; Bst[lc + 5][lr] = b1.y;
        Bst[lc + 6][lr] = b1.z; Bst[lc + 7][lr] = b1.w;
        __syncthreads();
#pragma unroll
        for (int kk = 0; kk < 32; kk++) {
            float av[4], bv[4];
            *(float4*)av = *(const float4*)&Ast[kk][ty * 4];
            *(float4*)bv = *(const float4*)&Bst[kk][tx * 4];
#pragma unroll
            for (int i = 0; i < 4; i++)
#pragma unroll
                for (int j = 0; j < 4; j++)
                    acc[i][j] = fmaf(av[i], bv[j], acc[i][j]);
        }
        __syncthreads();
    }
    float* obase = Xbuf + ((long)blockIdx.x * BS) * G4 + jt * 64;
#pragma unroll
    for (int i = 0; i < 4; i++) {
        int r = ty * 4 + i;
        float* orow = obase + (long)r * G4;
#pragma unroll
        for (int j = 0; j < 4; j++) {
            int col = tx * 4 + j;
            int gj = jt * 64 + col;
            orow[col] = acc[i][j] + b_ih[gj] + b_hh[gj];
        }
    }
}

// One LSTM step. grid 256 = 4 b-groups x 64 k-slices, block 256.
__global__ __launch_bounds__(256) void k_step(
    const float* __restrict__ Xt, const float* __restrict__ W_hh,
    float* __restrict__ hs_all, float* __restrict__ c_buf, int t) {
    const int bx = blockIdx.x;
    const int js = bx & 63;     // k-slice: kk base = js*8
    const int bg = bx >> 6;     // b-group
    const int tid = threadIdx.x;
    __shared__ float hT[512][17];
    __shared__ float g_lds[16][33];
    if (t > 0) {
        const float* hprev = hs_all + (long)(t - 1) * BS * HD + (long)bg * 16 * HD;
        int b = tid >> 4;
        int k0 = (tid & 15) * 32;
        const float* src = hprev + b * HD + k0;
#pragma unroll
        for (int m = 0; m < 32; m += 4) {
            float4 v = *(const float4*)(src + m);
            hT[k0 + m + 0][b] = v.x; hT[k0 + m + 1][b] = v.y;
            hT[k0 + m + 2][b] = v.z; hT[k0 + m + 3][b] = v.w;
        }
    }
    __syncthreads();
    const int b = tid & 15, jj = tid >> 4;
    const int r0 = jj, r1 = jj + 16;
    const long j0 = (long)(r0 >> 3) * HD + js * 8 + (r0 & 7);
    const long j1 = (long)(r1 >> 3) * HD + js * 8 + (r1 & 7);
    float acc0 = 0.f, acc1 = 0.f;
    if (t > 0) {
        const float* w0 = W_hh + j0 * HD;
        const float* w1 = W_hh + j1 * HD;
#pragma unroll 4
        for (int k = 0; k < HD; k += 4) {
            float4 wa = *(const float4*)(w0 + k);
            float4 wb = *(const float4*)(w1 + k);
            float h0 = hT[k][b], h1 = hT[k + 1][b], h2 = hT[k + 2][b], h3 = hT[k + 3][b];
            acc0 = fmaf(h0, wa.x, acc0); acc0 = fmaf(h1, wa.y, acc0);
            acc0 = fmaf(h2, wa.z, acc0); acc0 = fmaf(h3, wa.w, acc0);
            acc1 = fmaf(h0, wb.x, acc1); acc1 = fmaf(h1, wb.y, acc1);
            acc1 = fmaf(h2, wb.z, acc1); acc1 = fmaf(h3, wb.w, acc1);
        }
    }
    const int bglob = bg * 16 + b;
    g_lds[b][r0] = Xt[(long)bglob * G4 + j0] + acc0;
    g_lds[b][r1] = Xt[(long)bglob * G4 + j1] + acc1;
    __syncthreads();
    if (tid < 128) {
        int bb = tid & 15, kk = tid >> 4;   // kk 0..7
        float gi = g_lds[bb][kk];
        float gf = g_lds[bb][8 + kk];
        float gg = g_lds[bb][16 + kk];
        float go = g_lds[bb][24 + kk];
        float iv = sigm_f(gi), fv = sigm_f(gf), gv = tanh_f(gg), ov = sigm_f(go);
        int bg2 = bg * 16 + bb;
        long cidx = (long)bg2 * HD + js * 8 + kk;
        float c_old = (t > 0) ? c_buf[cidx] : 0.f;
        float c_new = fv * c_old + iv * gv;
        float h_new = ov * tanh_f(c_new);
        c_buf[cidx] = c_new;
        hs_all[(long)t * BS * HD + cidx] = h_new;
    }
}

// logits[b][v] = hs[b][:] . W_out[v][:] + b_out[v].  grid 786, block 256.
__global__ __launch_bounds__(256) void k_logits(
    const float* __restrict__ hsrow, const float* __restrict__ W_out,
    const float* __restrict__ b_out, float* __restrict__ logits) {
    __shared__ float Ast[32][68];
    __shared__ float Bst[32][68];
    const int v0 = blockIdx.x * 64;
    const int tid = threadIdx.x;
    const int tx = tid & 15, ty = tid >> 4;
    const int lr = tid >> 2;
    const int lc = (tid & 3) * 8;
    int vr = v0 + lr; if (vr > NV - 1) vr = NV - 1;
    const float* arow = hsrow + (long)lr * HD + lc;
    const float* wrow = W_out + (long)vr * HD + lc;
    float acc[4][4] = {};
    for (int k0 = 0; k0 < HD; k0 += 32) {
        float4 a0 = *(const float4*)(arow + k0);
        float4 a1 = *(const float4*)(arow + k0 + 4);
        float4 b0 = *(const float4*)(wrow + k0);
        float4 b1 = *(const float4*)(wrow + k0 + 4);
        Ast[lc + 0][lr] = a0.x; Ast[lc + 1][lr] = a0.y;
        Ast[lc + 2][lr] = a0.z; Ast[lc + 3][lr] = a0.w;
        Ast[lc + 4][lr] = a1.x; Ast[lc + 5][lr] = a1.y;
        Ast[lc + 6][lr] = a1.z; Ast[lc + 7][lr] = a1.w;
        Bst[lc + 0][lr] = b0.x; Bst[lc + 1][lr] = b0.y;
        Bst[lc + 2][lr] = b0.z; Bst[lc + 3][lr] = b0.w;
        Bst[lc + 4][lr] = b1.x; Bst[lc + 5][lr] = b1.y;
        Bst[lc + 6][lr] = b1.z; Bst[lc + 7][lr] = b1.w;
        __syncthreads();
#pragma unroll
        for (int kk = 0; kk < 32; kk++) {
            float av[4], bv[4];
            *(float4*)av = *(const float4*)&Ast[kk][ty * 4];
            *(float4*)bv = *(const float4*)&Bst[kk][tx * 4];
#pragma unroll
            for (int i = 0; i < 4; i++)
#pragma unroll
                for (int j = 0; j < 4; j++)
                    acc[i][j] = fmaf(av[i], bv[j], acc[i][j]);
        }
        __syncthreads();
    }
#pragma unroll
    for (int i = 0; i < 4; i++) {
        int b = ty * 4 + i;
#pragma unroll
        for (int j = 0; j < 4; j++) {
            int v = v0 + tx * 4 + j;
            if (v < NV) logits[(long)b * LS + v] = acc[i][j] + b_out[v];
        }
    }
}

// online logsumexp per batch row. grid 64, block 256.
__global__ __launch_bounds__(256) void k_lse(
    const float* __restrict__ logits, float* __restrict__ lse) {
    const int b = blockIdx.x;
    const float* row = logits + (long)b * LS;
    float m = -1e30f, s = 0.f;
    for (int v = threadIdx.x; v < NV; v += 256) {
        float x = row[v];
        if (x > m) { s = s * __expf(m - x) + 1.f; m = x; }
        else s += __expf(x - m);
    }
    for (int off = 32; off; off >>= 1) {
        float m2 = __shfl_down(m, off);
        float s2 = __shfl_down(s, off);
        float M = fmaxf(m, m2);
        s = s * __expf(m - M) + s2 * __expf(m2 - M);
        m = M;
    }
    __shared__ float ms[4], ss[4];
    int wid = threadIdx.x >> 6, lane = threadIdx.x & 63;
    if (lane == 0) { ms[wid] = m; ss[wid] = s; }
    __syncthreads();
    if (threadIdx.x == 0) {
        m = ms[0]; s = ss[0];
        for (int w = 1; w < 4; w++) {
            float M = fmaxf(m, ms[w]);
            s = s * __expf(m - M) + ss[w] * __expf(ms[w] - M);
            m = M;
        }
        lse[b] = m + __logf(s);
    }
}

__global__ __launch_bounds__(64) void k_loss(
    const float* __restrict__ logits, const float* __restrict__ lse,
    const int* __restrict__ tlines, float* __restrict__ out0) {
    int b = threadIdx.x;
    float v = logits[(long)b * LS + tlines[b]] - lse[b];
    for (int off = 32; off; off >>= 1) v += __shfl_down(v, off);
    if (b == 0) out0[0] = -v * (1.f / 64.f);
}

// partial[tc][h][e] = sum_{t in chunk} exp(ht^T hs_t)[h][e]; also exp_S0.
// grid (64, 4): 8x8 tiles of 64x64 over (h,e), 4 t-chunks of 64. block 256.
__global__ __launch_bounds__(256) void k_attn(
    const float* __restrict__ hs, float* __restrict__ eS0, float* __restrict__ part) {
    __shared__ float Att[64][68];
    __shared__ float Bsm[64][68];
    const int hti = blockIdx.x >> 3, eti = blockIdx.x & 7;
    const int tc = blockIdx.y;
    const int tid = threadIdx.x;
    const int lb = tid >> 2;
    const int lseg = (tid & 3) * 16;
    const float* ht = hs + (long)TE * BS * HD;
    {
        const float* src = ht + (long)lb * HD + hti * 64 + lseg;
#pragma unroll
        for (int m = 0; m < 16; m += 4)
            *(float4*)&Att[lb][lseg + m] = *(const float4*)(src + m);
    }
    const int ti = tid >> 4, tj = tid & 15;
    float ps[4][4] = {};
    for (int dt = 0; dt < 64; dt++) {
        const int t = tc * 64 + dt;
        __syncthreads();
        const float* src = hs + ((long)t * BS + lb) * HD + eti * 64 + lseg;
#pragma unroll
        for (int m = 0; m < 16; m += 4)
            *(float4*)&Bsm[lb][lseg + m] = *(const float4*)(src + m);
        __syncthreads();
        float acc[4][4] = {};
#pragma unroll 4
        for (int b = 0; b < 64; b++) {
            float av[4], bv[4];
            *(float4*)av = *(const float4*)&Att[b][ti * 4];
            *(float4*)bv = *(const float4*)&Bsm[b][tj * 4];
#pragma unroll
            for (int i = 0; i < 4; i++)
#pragma unroll
                for (int j = 0; j < 4; j++)
                    acc[i][j] = fmaf(av[i], bv[j], acc[i][j]);
        }
        const bool first = (tc == 0 && dt == 0);
#pragma unroll
        for (int i = 0; i < 4; i++)
#pragma unroll
            for (int j = 0; j < 4; j++) {
                float e = __expf(acc[i][j]);
                ps[i][j] += e;
                if (first)
                    eS0[(long)(hti * 64 + ti * 4 + i) * HD + eti * 64 + tj * 4 + j] = e;
            }
    }
#pragma unroll
    for (int i = 0; i < 4; i++)
#pragma unroll
        for (int j = 0; j < 4; j++)
            part[(long)tc * 262144 + (long)(hti * 64 + ti * 4 + i) * HD + eti * 64 + tj * 4 + j] = ps[i][j];
}

__global__ __launch_bounds__(256) void k_attn_fin(
    const float* __restrict__ eS0, const float* __restrict__ part,
    float* __restrict__ outat) {
    long i = (long)blockIdx.x * 256 + threadIdx.x;
    float d = part[i] + part[262144 + i] + part[2L * 262144 + i] + part[3L * 262144 + i];
    outat[i] = eS0[i] / d;
}

extern "C" void kernel_launch(void* const* d_in, const int* in_sizes, int n_in,
                              void* d_out, int out_size, void* d_ws, size_t ws_size,
                              hipStream_t stream) {
    (void)in_sizes; (void)n_in; (void)out_size; (void)ws_size;
    const int* input_lines  = (const int*)d_in[0];
    const int* target_lines = (const int*)d_in[1];
    const float* emb_in  = (const float*)d_in[2];
    const float* emb_tgt = (const float*)d_in[3];
    const float* W_ih = (const float*)d_in[4];
    const float* W_hh = (const float*)d_in[5];
    const float* b_ih = (const float*)d_in[6];
    const float* b_hh = (const float*)d_in[7];
    const float* W_out = (const float*)d_in[8];
    const float* b_out = (const float*)d_in[9];
    float* out = (float*)d_out;
    float* ws = (float*)d_ws;

    float* X      = ws;                      // 64*64*2048      = 8388608
    float* hs     = X + 8388608;             // 257*64*512      = 8421376
    float* cbuf   = hs + 8421376;            // 64*512          = 32768
    float* logits = cbuf + 32768;            // 64*50304        = 3219456
    float* lse    = logits + 3219456;        // 64
    float* eS0    = lse + 64;                // 262144
    float* part   = eS0 + 262144;            // 4*262144        = 1048576
    // total ~85.5 MB

    for (int c = 0; c < 4; ++c) {
        hipLaunchKernelGGL(k_x, dim3(64, 32), dim3(256), 0, stream,
                           input_lines, target_lines, emb_in, emb_tgt,
                           W_ih, b_ih, b_hh, X, c * 64);
        for (int dt = 0; dt < 64; ++dt) {
            int t = c * 64 + dt;
            hipLaunchKernelGGL(k_step, dim3(256), dim3(256), 0, stream,
                               X + (long)dt * BS * G4, W_hh, hs, cbuf, t);
        }
    }
    // decoder step folded in as t = 256 (x from emb_tgt[tgt0])
    hipLaunchKernelGGL(k_x, dim3(1, 32), dim3(256), 0, stream,
                       input_lines, target_lines, emb_in, emb_tgt,
                       W_ih, b_ih, b_hh, X, 256);
    hipLaunchKernelGGL(k_step, dim3(256), dim3(256), 0, stream,
                       X, W_hh, hs, cbuf, 256);

    hipLaunchKernelGGL(k_logits, dim3(786), dim3(256), 0, stream,
                       hs + (long)255 * BS * HD, W_out, b_out, logits);
    hipLaunchKernelGGL(k_lse, dim3(64), dim3(256), 0, stream, logits, lse);
    hipLaunchKernelGGL(k_loss, dim3(1), dim3(64), 0, stream,
                       logits, lse, target_lines, out);
    hipLaunchKernelGGL(k_attn, dim3(64, 4), dim3(256), 0, stream, hs, eS0, part);
    hipLaunchKernelGGL(k_attn_fin, dim3(1024), dim3(256), 0, stream, eS0, part, out + 1);
}